// Round 6
// baseline (287.850 us; speedup 1.0000x reference)
//
#include <hip/hip_runtime.h>
#include <hip/hip_bf16.h>

#define CIN 128
#define COUT 512
#define NEG_SLOPE 0.1f

typedef __bf16 bf16x8 __attribute__((ext_vector_type(8)));
typedef float f32x4 __attribute__((ext_vector_type(4)));

static __device__ __forceinline__ unsigned short f2bf(float f) {
  unsigned int u = __builtin_bit_cast(unsigned int, f);
  unsigned int lsb = (u >> 16) & 1u;
  u += 0x7fffu + lsb;  // round-to-nearest-even
  return (unsigned short)(u >> 16);
}
static __device__ __forceinline__ float bf_lo(unsigned int u) {
  return __builtin_bit_cast(float, u << 16);
}
static __device__ __forceinline__ float bf_hi(unsigned int u) {
  return __builtin_bit_cast(float, u & 0xffff0000u);
}
static __device__ __forceinline__ unsigned int pack2(float lo, float hi) {
  return (unsigned int)f2bf(lo) | ((unsigned int)f2bf(hi) << 16);
}

// Fused int64/int32 self-detection + decode + degree count + per-edge rank.
// Detection: in int64 storage every odd int32 word of the src half is 0
// (node ids < 2^31). Each block votes over its own 256 odd words -- safe
// addresses (2e+1 < 2E) in BOTH encodings.
__global__ void decode_count_kernel(const int* __restrict__ raw,
                                    int* __restrict__ srcA, int* __restrict__ dstA,
                                    int* __restrict__ rank, int* __restrict__ cnt,
                                    int E, int N) {
  __shared__ int s_is32;
  if (threadIdx.x == 0) s_is32 = 0;
  __syncthreads();
  int e = blockIdx.x * blockDim.x + threadIdx.x;
  int probe = 0;
  if (e < E) probe = raw[2 * e + 1];
  if (probe != 0) s_is32 = 1;  // benign race: any writer writes 1
  __syncthreads();
  if (e >= E) return;
  int s, d;
  if (!s_is32) {  // int64: value in low word of each 8B pair
    int2 sv = ((const int2*)raw)[e];
    int2 dv = ((const int2*)raw)[E + e];
    s = sv.x;
    d = dv.x;
  } else {  // int32 packed
    s = raw[e];
    d = raw[E + e];
  }
  if ((unsigned)s >= (unsigned)N) s = 0;
  if ((unsigned)d >= (unsigned)N) d = 0;
  srcA[e] = s;
  dstA[e] = d;
  rank[e] = atomicAdd(&cnt[d], 1);
}

// Single-pass scan: block-local exclusive scan + block base from a global
// atomic cursor (CSR segments in block-arrival order -- valid partition).
__global__ __launch_bounds__(256) void scan_kernel(const int* __restrict__ cnt,
                                                   int* __restrict__ rowptr,
                                                   int* __restrict__ gcur, int N) {
  __shared__ int buf[256];
  __shared__ int sbase;
  int tid = threadIdx.x;
  int base = blockIdx.x * 1024 + tid * 4;
  int v[4];
  int tot = 0;
#pragma unroll
  for (int k = 0; k < 4; ++k) {
    int i = base + k;
    v[k] = (i < N) ? cnt[i] : 0;
    tot += v[k];
  }
  buf[tid] = tot;
  __syncthreads();
  for (int off = 1; off < 256; off <<= 1) {
    int t = (tid >= off) ? buf[tid - off] : 0;
    __syncthreads();
    buf[tid] += t;
    __syncthreads();
  }
  if (tid == 255) sbase = atomicAdd(gcur, buf[255]);  // device-scope
  __syncthreads();
  int run = sbase + buf[tid] - tot;
#pragma unroll
  for (int k = 0; k < 4; ++k) {
    int i = base + k;
    if (i < N) rowptr[i] = run;
    run += v[k];
  }
}

// Merged scatter (idx < E) + xscale (idx < N*32) + W->bf16 MFMA-FRAGMENT
// SHUFFLE (next 8192 16B-groups). Wshuf: fragment element j of
// (wave, nt, kk, lane) at Wshuf[(((wave*8+nt)*4+kk)*64 + lane)*8 + j] so each
// gemm wf load is 64 lanes x 16 B contiguous (1 KB/instr, zero overfetch).
__global__ __launch_bounds__(256) void scatter_prep_kernel(
    const int* __restrict__ srcA, const int* __restrict__ dstA,
    const int* __restrict__ rank, const int* __restrict__ rowptr,
    int* __restrict__ col, int E,
    const float* __restrict__ x, const int* __restrict__ cnt,
    unsigned short* __restrict__ xs,
    const float* __restrict__ W, unsigned short* __restrict__ Wbf, int N) {
  int idx = blockIdx.x * blockDim.x + threadIdx.x;
  if (idx < E) {
    int d = dstA[idx];
    col[rowptr[d] + rank[idx]] = srcA[idx];
  }
  int nx = N * (CIN / 4);
  if (idx < nx) {
    int row = idx >> 5;  // 32 float4 groups per row
    float d = 1.0f / sqrtf((float)(cnt[row] + 1));  // +1 = self-loop
    float4 v = ((const float4*)x)[idx];
    ushort4 o;
    o.x = f2bf(v.x * d); o.y = f2bf(v.y * d); o.z = f2bf(v.z * d); o.w = f2bf(v.w * d);
    ((ushort4*)xs)[idx] = o;
  } else {
    int t = idx - nx;  // one 16B fragment (8 bf16) of Wshuf
    if (t < (COUT * CIN / 8)) {
      int lane = t & 63;
      int kk = (t >> 6) & 3;
      int nt = (t >> 8) & 7;
      int wv = t >> 11;  // 0..3
      int row = wv * 128 + nt * 16 + (lane & 15);
      int c = kk * 32 + (lane >> 4) * 8;
      const float* src = W + (size_t)row * CIN + c;
      float4 v0 = *(const float4*)src;
      float4 v1 = *(const float4*)(src + 4);
      ushort4 o0, o1;
      o0.x = f2bf(v0.x); o0.y = f2bf(v0.y); o0.z = f2bf(v0.z); o0.w = f2bf(v0.w);
      o1.x = f2bf(v1.x); o1.y = f2bf(v1.y); o1.z = f2bf(v1.z); o1.w = f2bf(v1.w);
      ((ushort4*)Wbf)[2 * t] = o0;
      ((ushort4*)Wbf)[2 * t + 1] = o1;
    }
  }
}

// Gather hop over pre-scaled bf16 rows (256 B/row). One node per wave; grp
// (lane>>4) picks the row, sub (lane&15) the 16B chunk -> wave-uniform trip
// count. Main loop 16 rows/step (4-deep per lane); tail unrolled 8/4/masked.
// Output: di^2 * (self + sum) -> h1s (feeds the fused hop2+gemm).
__global__ __launch_bounds__(256) void hop1_kernel(
    const unsigned short* __restrict__ Xs,
    const int* __restrict__ rowptr, const int* __restrict__ cnt,
    const int* __restrict__ col, unsigned short* __restrict__ Y, int N) {
  int lane = threadIdx.x & 63;
  int wid = threadIdx.x >> 6;
  int node = blockIdx.x * 4 + wid;
  if (node >= N) return;
  int sub = lane & 15;
  int grp = lane >> 4;
  int beg = rowptr[node];
  int num = cnt[node];
  const uint4* X4 = (const uint4*)Xs;  // one row = 16 uint4
  float acc[8] = {0.f, 0.f, 0.f, 0.f, 0.f, 0.f, 0.f, 0.f};
  if (grp == 0) {  // self-loop term
    uint4 s = X4[(size_t)node * 16 + sub];
    acc[0] = bf_lo(s.x); acc[1] = bf_hi(s.x);
    acc[2] = bf_lo(s.y); acc[3] = bf_hi(s.y);
    acc[4] = bf_lo(s.z); acc[5] = bf_hi(s.z);
    acc[6] = bf_lo(s.w); acc[7] = bf_hi(s.w);
  }
  const int* cp = col + beg;
  int kb = 0;
  for (; kb + 16 <= num; kb += 16) {
    int j0 = cp[kb + grp];
    int j1 = cp[kb + 4 + grp];
    int j2 = cp[kb + 8 + grp];
    int j3 = cp[kb + 12 + grp];
    uint4 v0 = X4[(size_t)j0 * 16 + sub];
    uint4 v1 = X4[(size_t)j1 * 16 + sub];
    uint4 v2 = X4[(size_t)j2 * 16 + sub];
    uint4 v3 = X4[(size_t)j3 * 16 + sub];
    acc[0] += bf_lo(v0.x); acc[1] += bf_hi(v0.x);
    acc[2] += bf_lo(v0.y); acc[3] += bf_hi(v0.y);
    acc[4] += bf_lo(v0.z); acc[5] += bf_hi(v0.z);
    acc[6] += bf_lo(v0.w); acc[7] += bf_hi(v0.w);
    acc[0] += bf_lo(v1.x); acc[1] += bf_hi(v1.x);
    acc[2] += bf_lo(v1.y); acc[3] += bf_hi(v1.y);
    acc[4] += bf_lo(v1.z); acc[5] += bf_hi(v1.z);
    acc[6] += bf_lo(v1.w); acc[7] += bf_hi(v1.w);
    acc[0] += bf_lo(v2.x); acc[1] += bf_hi(v2.x);
    acc[2] += bf_lo(v2.y); acc[3] += bf_hi(v2.y);
    acc[4] += bf_lo(v2.z); acc[5] += bf_hi(v2.z);
    acc[6] += bf_lo(v2.w); acc[7] += bf_hi(v2.w);
    acc[0] += bf_lo(v3.x); acc[1] += bf_hi(v3.x);
    acc[2] += bf_lo(v3.y); acc[3] += bf_hi(v3.y);
    acc[4] += bf_lo(v3.z); acc[5] += bf_hi(v3.z);
    acc[6] += bf_lo(v3.w); acc[7] += bf_hi(v3.w);
  }
  int rem = num - kb;  // [0,16)
  if (rem >= 8) {      // 2-deep round
    int j0 = cp[kb + grp];
    int j1 = cp[kb + 4 + grp];
    uint4 v0 = X4[(size_t)j0 * 16 + sub];
    uint4 v1 = X4[(size_t)j1 * 16 + sub];
    acc[0] += bf_lo(v0.x); acc[1] += bf_hi(v0.x);
    acc[2] += bf_lo(v0.y); acc[3] += bf_hi(v0.y);
    acc[4] += bf_lo(v0.z); acc[5] += bf_hi(v0.z);
    acc[6] += bf_lo(v0.w); acc[7] += bf_hi(v0.w);
    acc[0] += bf_lo(v1.x); acc[1] += bf_hi(v1.x);
    acc[2] += bf_lo(v1.y); acc[3] += bf_hi(v1.y);
    acc[4] += bf_lo(v1.z); acc[5] += bf_hi(v1.z);
    acc[6] += bf_lo(v1.w); acc[7] += bf_hi(v1.w);
    kb += 8; rem -= 8;
  }
  if (rem >= 4) {
    int j0 = cp[kb + grp];
    uint4 v0 = X4[(size_t)j0 * 16 + sub];
    acc[0] += bf_lo(v0.x); acc[1] += bf_hi(v0.x);
    acc[2] += bf_lo(v0.y); acc[3] += bf_hi(v0.y);
    acc[4] += bf_lo(v0.z); acc[5] += bf_hi(v0.z);
    acc[6] += bf_lo(v0.w); acc[7] += bf_hi(v0.w);
    kb += 4; rem -= 4;
  }
  if (grp < rem) {  // rem in [0,4)
    int j0 = cp[kb + grp];
    uint4 v0 = X4[(size_t)j0 * 16 + sub];
    acc[0] += bf_lo(v0.x); acc[1] += bf_hi(v0.x);
    acc[2] += bf_lo(v0.y); acc[3] += bf_hi(v0.y);
    acc[4] += bf_lo(v0.z); acc[5] += bf_hi(v0.z);
    acc[6] += bf_lo(v0.w); acc[7] += bf_hi(v0.w);
  }
#pragma unroll
  for (int r = 0; r < 8; ++r) acc[r] += __shfl_xor(acc[r], 16, 64);
#pragma unroll
  for (int r = 0; r < 8; ++r) acc[r] += __shfl_xor(acc[r], 32, 64);
  if (grp == 0) {
    float di = 1.0f / sqrtf((float)(num + 1));
    float sc = di * di;
    uint4 o;
    o.x = pack2(acc[0] * sc, acc[1] * sc);
    o.y = pack2(acc[2] * sc, acc[3] * sc);
    o.z = pack2(acc[4] * sc, acc[5] * sc);
    o.w = pack2(acc[6] * sc, acc[7] * sc);
    ((uint4*)Y)[(size_t)node * 16 + sub] = o;
  }
}

// FUSED hop2 + GEMM + bias + LeakyReLU. Block = 32 nodes.
// Phase 1: 4 waves x 8 nodes each run the gather hop (same 16-rows-in-flight
//   loop as hop1) over h1s, scale by di, pack bf16, and stage rows in LDS
//   ([32][136] shorts, 272 B stride -> <=2-way banks on write and read).
//   Kills the 25.6 MB h2 HBM round-trip + one launch, and lets gather-phase
//   blocks overlap MFMA/store-phase blocks on disjoint pipes.
// Phase 2: af fragments from LDS; W pre-shuffled fragment-order (1 KB/instr
//   contiguous loads); swapped-operand MFMA (lane&15 = m, quad*4+reg = n).
// Phase 3: LDS-staged dense epilogue (1 KB contiguous per wave store instr).
// The 33 KB epilogue tile unions with the 8.7 KB h2 staging area.
__global__ __launch_bounds__(256) void hopgemm_kernel(
    const unsigned short* __restrict__ Xs,  // h1s (workspace -- NOT d_out!)
    const int* __restrict__ rowptr, const int* __restrict__ cnt,
    const int* __restrict__ col,
    const unsigned short* __restrict__ Wbf, const float* __restrict__ bias,
    float* __restrict__ out, int N) {
  __shared__ char smem[16 * 516 * 4];          // 33 KB
  unsigned short* s_h2 = (unsigned short*)smem;  // [32][136] during phases 1-2
  float* tile = (float*)smem;                    // [16][516] during phase 3

  int lane = threadIdx.x & 63;
  int wave = threadIdx.x >> 6;
  int sub = lane & 15;
  int grp = lane >> 4;
  int mbase = blockIdx.x * 32;
  const uint4* X4 = (const uint4*)Xs;

  // ---- Phase 1: hop 8 nodes per wave into LDS ----
  for (int t = 0; t < 8; ++t) {
    int nl = wave * 8 + t;
    int node = mbase + nl;
    int beg = 0, num = 0;
    if (node < N) { beg = rowptr[node]; num = cnt[node]; }
    float acc[8] = {0.f, 0.f, 0.f, 0.f, 0.f, 0.f, 0.f, 0.f};
    if (grp == 0 && node < N) {  // self-loop term
      uint4 s = X4[(size_t)node * 16 + sub];
      acc[0] = bf_lo(s.x); acc[1] = bf_hi(s.x);
      acc[2] = bf_lo(s.y); acc[3] = bf_hi(s.y);
      acc[4] = bf_lo(s.z); acc[5] = bf_hi(s.z);
      acc[6] = bf_lo(s.w); acc[7] = bf_hi(s.w);
    }
    const int* cp = col + beg;
    int kb = 0;
    for (; kb + 16 <= num; kb += 16) {
      int j0 = cp[kb + grp];
      int j1 = cp[kb + 4 + grp];
      int j2 = cp[kb + 8 + grp];
      int j3 = cp[kb + 12 + grp];
      uint4 v0 = X4[(size_t)j0 * 16 + sub];
      uint4 v1 = X4[(size_t)j1 * 16 + sub];
      uint4 v2 = X4[(size_t)j2 * 16 + sub];
      uint4 v3 = X4[(size_t)j3 * 16 + sub];
      acc[0] += bf_lo(v0.x); acc[1] += bf_hi(v0.x);
      acc[2] += bf_lo(v0.y); acc[3] += bf_hi(v0.y);
      acc[4] += bf_lo(v0.z); acc[5] += bf_hi(v0.z);
      acc[6] += bf_lo(v0.w); acc[7] += bf_hi(v0.w);
      acc[0] += bf_lo(v1.x); acc[1] += bf_hi(v1.x);
      acc[2] += bf_lo(v1.y); acc[3] += bf_hi(v1.y);
      acc[4] += bf_lo(v1.z); acc[5] += bf_hi(v1.z);
      acc[6] += bf_lo(v1.w); acc[7] += bf_hi(v1.w);
      acc[0] += bf_lo(v2.x); acc[1] += bf_hi(v2.x);
      acc[2] += bf_lo(v2.y); acc[3] += bf_hi(v2.y);
      acc[4] += bf_lo(v2.z); acc[5] += bf_hi(v2.z);
      acc[6] += bf_lo(v2.w); acc[7] += bf_hi(v2.w);
      acc[0] += bf_lo(v3.x); acc[1] += bf_hi(v3.x);
      acc[2] += bf_lo(v3.y); acc[3] += bf_hi(v3.y);
      acc[4] += bf_lo(v3.z); acc[5] += bf_hi(v3.z);
      acc[6] += bf_lo(v3.w); acc[7] += bf_hi(v3.w);
    }
    int rem = num - kb;  // [0,16)
    if (rem >= 8) {
      int j0 = cp[kb + grp];
      int j1 = cp[kb + 4 + grp];
      uint4 v0 = X4[(size_t)j0 * 16 + sub];
      uint4 v1 = X4[(size_t)j1 * 16 + sub];
      acc[0] += bf_lo(v0.x); acc[1] += bf_hi(v0.x);
      acc[2] += bf_lo(v0.y); acc[3] += bf_hi(v0.y);
      acc[4] += bf_lo(v0.z); acc[5] += bf_hi(v0.z);
      acc[6] += bf_lo(v0.w); acc[7] += bf_hi(v0.w);
      acc[0] += bf_lo(v1.x); acc[1] += bf_hi(v1.x);
      acc[2] += bf_lo(v1.y); acc[3] += bf_hi(v1.y);
      acc[4] += bf_lo(v1.z); acc[5] += bf_hi(v1.z);
      acc[6] += bf_lo(v1.w); acc[7] += bf_hi(v1.w);
      kb += 8; rem -= 8;
    }
    if (rem >= 4) {
      int j0 = cp[kb + grp];
      uint4 v0 = X4[(size_t)j0 * 16 + sub];
      acc[0] += bf_lo(v0.x); acc[1] += bf_hi(v0.x);
      acc[2] += bf_lo(v0.y); acc[3] += bf_hi(v0.y);
      acc[4] += bf_lo(v0.z); acc[5] += bf_hi(v0.z);
      acc[6] += bf_lo(v0.w); acc[7] += bf_hi(v0.w);
      kb += 4; rem -= 4;
    }
    if (grp < rem) {
      int j0 = cp[kb + grp];
      uint4 v0 = X4[(size_t)j0 * 16 + sub];
      acc[0] += bf_lo(v0.x); acc[1] += bf_hi(v0.x);
      acc[2] += bf_lo(v0.y); acc[3] += bf_hi(v0.y);
      acc[4] += bf_lo(v0.z); acc[5] += bf_hi(v0.z);
      acc[6] += bf_lo(v0.w); acc[7] += bf_hi(v0.w);
    }
#pragma unroll
    for (int r = 0; r < 8; ++r) acc[r] += __shfl_xor(acc[r], 16, 64);
#pragma unroll
    for (int r = 0; r < 8; ++r) acc[r] += __shfl_xor(acc[r], 32, 64);
    if (grp == 0) {
      uint4 o = {0u, 0u, 0u, 0u};
      if (node < N) {
        float di = 1.0f / sqrtf((float)(num + 1));
        o.x = pack2(acc[0] * di, acc[1] * di);
        o.y = pack2(acc[2] * di, acc[3] * di);
        o.z = pack2(acc[4] * di, acc[5] * di);
        o.w = pack2(acc[6] * di, acc[7] * di);
      }
      *(uint4*)&s_h2[nl * 136 + sub * 8] = o;
    }
  }
  __syncthreads();

  // ---- Phase 2: fragments + MFMA ----
  int quad = grp;       // lane>>4
  int l16 = sub;        // lane&15
  bf16x8 af[2][4];
#pragma unroll
  for (int kk = 0; kk < 4; ++kk) {
    af[0][kk] = *(const bf16x8*)&s_h2[l16 * 136 + kk * 32 + quad * 8];
    af[1][kk] = *(const bf16x8*)&s_h2[(16 + l16) * 136 + kk * 32 + quad * 8];
  }

  const bf16x8* Wf = (const bf16x8*)Wbf;  // fragment-ordered
  int nbase = wave * 128;
  f32x4 acc0[8], acc1[8];
#pragma unroll
  for (int nt = 0; nt < 8; ++nt) {
    bf16x8 wf[4];
#pragma unroll
    for (int kk = 0; kk < 4; ++kk)
      wf[kk] = Wf[(((wave * 8 + nt) * 4 + kk) << 6) + lane];
    f32x4 a0 = {}, a1 = {};
#pragma unroll
    for (int kk = 0; kk < 4; ++kk) {
      a0 = __builtin_amdgcn_mfma_f32_16x16x32_bf16(wf[kk], af[0][kk], a0, 0, 0, 0);
      a1 = __builtin_amdgcn_mfma_f32_16x16x32_bf16(wf[kk], af[1][kk], a1, 0, 0, 0);
    }
    acc0[nt] = a0;
    acc1[nt] = a1;
  }
  __syncthreads();  // everyone done reading s_h2; LDS becomes the out tile

  // ---- Phase 3: LDS-staged dense epilogue ----
#pragma unroll
  for (int half = 0; half < 2; ++half) {
    if (half) __syncthreads();  // WAR: previous half streamed out
#pragma unroll
    for (int nt = 0; nt < 8; ++nt) {
      int n0 = nbase + nt * 16 + quad * 4;
      float4 bv = *(const float4*)(bias + n0);
      f32x4 a = half ? acc1[nt] : acc0[nt];
      float4 o;
      o.x = a[0] + bv.x; o.x = (o.x >= 0.f) ? o.x : NEG_SLOPE * o.x;
      o.y = a[1] + bv.y; o.y = (o.y >= 0.f) ? o.y : NEG_SLOPE * o.y;
      o.z = a[2] + bv.z; o.z = (o.z >= 0.f) ? o.z : NEG_SLOPE * o.z;
      o.w = a[3] + bv.w; o.w = (o.w >= 0.f) ? o.w : NEG_SLOPE * o.w;
      *(float4*)&tile[l16 * 516 + n0] = o;
    }
    __syncthreads();
#pragma unroll
    for (int it = 0; it < 8; ++it) {
      int r = it * 2 + (threadIdx.x >> 7);
      int c = (threadIdx.x & 127) * 4;
      int m = mbase + half * 16 + r;
      if (m < N) *(float4*)(out + (size_t)m * COUT + c) = *(const float4*)&tile[r * 516 + c];
    }
  }
}

static inline size_t align_up(size_t v, size_t a) { return (v + a - 1) & ~(a - 1); }

extern "C" void kernel_launch(void* const* d_in, const int* in_sizes, int n_in,
                              void* d_out, int out_size, void* d_ws, size_t ws_size,
                              hipStream_t stream) {
  const float* x = (const float*)d_in[0];
  const int* edge_raw = (const int*)d_in[1];
  const float* W = (const float*)d_in[2];
  const float* b = (const float*)d_in[3];
  float* out = (float*)d_out;

  const int N = in_sizes[0] / CIN;
  const int E = in_sizes[1] / 2;
  const int NB = (N + 1023) / 1024;  // scan blocks (49 for N=50000)

  // Workspace layout. gcur sits directly before cnt so ONE memset zeroes both.
  // h1s lives in WORKSPACE (not d_out tail): the fused hopgemm writes `out`
  // while other blocks still gather from h1s -- d_out placement would race.
  char* w = (char*)d_ws;
  int* gcur = (int*)w;            w += 256;
  int* cnt = (int*)w;             w += align_up((size_t)N * 4, 256);
  int* rowptr = (int*)w;          w += align_up((size_t)N * 4, 256);
  int* srcA = (int*)w;            w += align_up((size_t)E * 4, 256);
  int* dstA = (int*)w;            w += align_up((size_t)E * 4, 256);
  int* rank = (int*)w;            w += align_up((size_t)E * 4, 256);
  int* col = (int*)w;             w += align_up((size_t)E * 4, 256);
  unsigned short* h1s = (unsigned short*)w;   w += align_up((size_t)N * CIN * 2, 256);
  unsigned short* Wbf = (unsigned short*)w;   w += align_up((size_t)COUT * CIN * 2, 256);

  // xs in the tail of d_out: dead before hopgemm's first out-write (consumed
  // entirely by hop1, which completes before hopgemm launches).
  size_t outb = (size_t)out_size * sizeof(float);
  size_t rowb = (size_t)N * CIN * sizeof(unsigned short);
  unsigned short* xs = (unsigned short*)((char*)d_out + (outb - rowb));

  hipMemsetAsync(gcur, 0, 256 + (size_t)N * sizeof(int), stream);

  decode_count_kernel<<<(E + 255) / 256, 256, 0, stream>>>(edge_raw, srcA, dstA, rank, cnt, E, N);
  scan_kernel<<<NB, 256, 0, stream>>>(cnt, rowptr, gcur, N);

  int prep_elems = N * (CIN / 4) + COUT * CIN / 8;
  int sp_threads = (E > prep_elems) ? E : prep_elems;
  scatter_prep_kernel<<<(sp_threads + 255) / 256, 256, 0, stream>>>(
      srcA, dstA, rank, rowptr, col, E, x, cnt, xs, W, Wbf, N);

  hop1_kernel<<<(N + 3) / 4, 256, 0, stream>>>(xs, rowptr, cnt, col, h1s, N);

  hopgemm_kernel<<<(N + 31) / 32, 256, 0, stream>>>(h1s, rowptr, cnt, col, Wbf, b, out, N);
}